// Round 1
// baseline (791.013 us; speedup 1.0000x reference)
//
#include <hip/hip_runtime.h>
#include <math.h>

// MAGNO decoder, MI355X. Shapes fixed by the reference:
//   B=2, NL=2048, NQ=16384, CD=2, CIN=H=64, PH=256, COUT=3, K=32, scales {1,2}.
// Design notes:
//  * One wave (64 lanes) per query; lane = channel (0..63).
//  * Neighbor search: compact all latents with d2 <= r2^2 (CAP 512, mean ~78),
//    then either take all (<=32) or iteratively extract the 32 smallest by
//    (d2, latent_idx) lexicographic key == jax.lax.top_k stable selection set.
//  * d2 uses __fmul_rn/__fadd_rn (no contraction) so mask/top-32 boundary
//    decisions are bit-exact vs the fp32 reference.
//  * Edge MLP: layer0 factors into y-part (2 FMA) + per-query q-part.
//    Layers 1/2: weight COLUMN held in VGPRs per lane (64+64 regs), activation
//    broadcast via v_readlane -> FMA with SGPR operand. 1 readlane + 1 FMA per MAC.
//  * Both radius scales share one MLP pass (valid1 subset of valid2).
//  * Projection MLP is a second small kernel reading `decoded` from d_ws.

#define NLAT 2048
#define NQRY 16384
#define NBATCH 2
#define KNB 32
#define CAP 512

__device__ __forceinline__ float rlane(float v, int l) {
  return __uint_as_float(__builtin_amdgcn_readlane(__float_as_uint(v), l));
}

__device__ __forceinline__ float gelu_exact(float x) {
  // jax.nn.gelu(approximate=False): 0.5*x*(1+erf(x/sqrt(2)))
  return 0.5f * x * (1.0f + erff(x * 0.70710678118654752440f));
}

__launch_bounds__(64)
__global__ void magno_main(const float* __restrict__ lat,   // [NL,2]
                           const float* __restrict__ rn,    // [B,NL,64]
                           const float* __restrict__ qc,    // [B,NQ,2]
                           const float* __restrict__ w_e0, const float* __restrict__ b_e0,
                           const float* __restrict__ w_e1, const float* __restrict__ b_e1,
                           const float* __restrict__ w_e2, const float* __restrict__ b_e2,
                           const float* __restrict__ w_sw0, const float* __restrict__ b_sw0,
                           const float* __restrict__ w_sw1, const float* __restrict__ b_sw1,
                           float* __restrict__ dec_out)     // [B*NQ,64]
{
  const int j  = threadIdx.x;            // channel lane 0..63
  const int gq = blockIdx.x;             // global query 0..B*NQ-1
  const int b  = gq >> 14;               // / NQ

  // radius^2 computed through the same f64 path as the Python reference
  const float r1sq = (float)(0.055 * 0.055);                 // scale 1.0
  const float r2sq = (float)((0.055 * 2.0) * (0.055 * 2.0)); // scale 2.0

  __shared__ float cand_d2[CAP];
  __shared__ int   cand_idx[CAP];
  __shared__ float sel_d2[KNB];
  __shared__ int   sel_idx[KNB];

  // ---- per-query / per-lane setup ----------------------------------------
  const float q0 = qc[(size_t)gq * 2 + 0];
  const float q1 = qc[(size_t)gq * 2 + 1];

  const float we0c0 = w_e0[j];
  const float we0c1 = w_e0[64 + j];
  const float qpart = fmaf(q0, w_e0[128 + j], fmaf(q1, w_e0[192 + j], b_e0[j]));
  const float be1j  = b_e1[j];
  const float be2j  = b_e2[j];

  float we1c[64], we2c[64];              // weight columns, register-resident
#pragma unroll
  for (int i = 0; i < 64; ++i) {
    we1c[i] = w_e1[i * 64 + j];
    we2c[i] = w_e2[i * 64 + j];
  }

  // ---- phase 1: radius search + compaction -------------------------------
  int nc = 0;
  for (int t = 0; t < NLAT; t += 64) {
    const int l = t + j;
    const float yx = lat[2 * l], yy = lat[2 * l + 1];
    const float dx = q0 - yx, dy = q1 - yy;
    const float d2 = __fadd_rn(__fmul_rn(dx, dx), __fmul_rn(dy, dy));
    const bool hit = d2 <= r2sq;
    const unsigned long long mask = __ballot(hit);
    if (hit) {
      const int pos = nc + __popcll(mask & (((unsigned long long)1 << j) - 1ull));
      if (pos < CAP) { cand_d2[pos] = d2; cand_idx[pos] = l; }
    }
    nc += (int)__popcll(mask);
  }
  if (nc > CAP) nc = CAP;  // statistically unreachable (mean 78, cap ~49 sigma)
  __syncthreads();

  // ---- phase 1b: select the <=32 nearest ---------------------------------
  int n_sel;
  if (nc <= KNB) {
    n_sel = nc;                           // all candidates are the top-32 subset
    if (j < nc) { sel_d2[j] = cand_d2[j]; sel_idx[j] = cand_idx[j]; }
    __syncthreads();
  } else {
    n_sel = KNB;                          // 32 nearest, all within r2
    for (int r = 0; r < KNB; ++r) {
      unsigned long long best = ~0ull;
      for (int t = j; t < nc; t += 64) {
        const unsigned long long key =
            ((unsigned long long)__float_as_uint(cand_d2[t]) << 32) | (unsigned)t;
        if (key < best) best = key;
      }
#pragma unroll
      for (int off = 32; off > 0; off >>= 1) {
        const unsigned long long o = __shfl_xor(best, off);
        if (o < best) best = o;
      }
      if (j == 0) {
        const int pos = (int)(best & 0xffffffffu);
        sel_d2[r]  = __uint_as_float((unsigned)(best >> 32));
        sel_idx[r] = cand_idx[pos];
        cand_d2[pos] = __uint_as_float(0x7f800000u);  // +inf: claimed
      }
      __syncthreads();
    }
  }

  // ---- phase 2: edge MLP over selected pairs, dual-scale accumulate ------
  float accA = 0.f;   // scale 2 (all selected valid)
  float accB = 0.f;   // scale 1 (d2 <= r1sq)
  int   cnt1 = 0;

  for (int e = 0; e < n_sel; ++e) {
    const float d2e = sel_d2[e];
    int ie = sel_idx[e];
    ie = __builtin_amdgcn_readfirstlane(ie);

    const float yx = lat[2 * ie], yy = lat[2 * ie + 1];
    const float h1 = gelu_exact(fmaf(yx, we0c0, fmaf(yy, we0c1, qpart)));

    float a0 = be1j, a1 = 0.f, a2 = 0.f, a3 = 0.f;
#pragma unroll
    for (int i = 0; i < 64; i += 4) {
      a0 = fmaf(rlane(h1, i + 0), we1c[i + 0], a0);
      a1 = fmaf(rlane(h1, i + 1), we1c[i + 1], a1);
      a2 = fmaf(rlane(h1, i + 2), we1c[i + 2], a2);
      a3 = fmaf(rlane(h1, i + 3), we1c[i + 3], a3);
    }
    const float h2 = gelu_exact((a0 + a1) + (a2 + a3));

    float c0 = be2j, c1 = 0.f, c2 = 0.f, c3 = 0.f;
#pragma unroll
    for (int i = 0; i < 64; i += 4) {
      c0 = fmaf(rlane(h2, i + 0), we2c[i + 0], c0);
      c1 = fmaf(rlane(h2, i + 1), we2c[i + 1], c1);
      c2 = fmaf(rlane(h2, i + 2), we2c[i + 2], c2);
      c3 = fmaf(rlane(h2, i + 3), we2c[i + 3], c3);
    }
    const float h3 = (c0 + c1) + (c2 + c3);

    const float fv = rn[((size_t)b * NLAT + ie) * 64 + j];
    const float cv = h3 * fv;
    accA += cv;
    const bool v1 = d2e <= r1sq;
    if (v1) accB += cv;
    cnt1 += v1 ? 1 : 0;
  }

  // ---- phase 3: scale-mix softmax weights + combine ----------------------
  float t = 0.f;
  if (j < 16) {
    t = fmaf(q0, w_sw0[j], fmaf(q1, w_sw0[16 + j], b_sw0[j]));
    t = t > 0.f ? t : 0.f;               // relu
  }
  float z0 = b_sw1[0], z1 = b_sw1[1];
#pragma unroll
  for (int l = 0; l < 16; ++l) {
    const float s = rlane(t, l);
    z0 = fmaf(s, w_sw1[2 * l + 0], z0);
    z1 = fmaf(s, w_sw1[2 * l + 1], z1);
  }
  const float m  = fmaxf(z0, z1);
  const float e0 = expf(z0 - m), e1 = expf(z1 - m);
  const float inv = 1.f / (e0 + e1);
  const float sw0 = e0 * inv, sw1 = e1 * inv;

  const float c1f = (float)(cnt1 > 0 ? cnt1 : 1);
  const float c2f = (float)(n_sel > 0 ? n_sel : 1);
  const float decoded = sw0 * (accB / c1f) + sw1 * (accA / c2f);

  dec_out[(size_t)gq * 64 + j] = decoded;
}

// Projection ChannelMLP: [B*NQ,64] -> gelu([.,64]@[64,256]+b) @ [256,3] + b
// grid 2048 blocks x 256 threads; each wave owns 4 queries (amortizes weight loads).
__launch_bounds__(256)
__global__ void magno_proj(const float* __restrict__ dec,   // [B*NQ,64]
                           const float* __restrict__ w_p0,  // [64,256]
                           const float* __restrict__ b_p0,  // [256]
                           const float* __restrict__ w_p1,  // [256,3]
                           const float* __restrict__ b_p1,  // [3]
                           float* __restrict__ out)         // [B*NQ,3]
{
  const int lane = threadIdx.x & 63;
  const int wv   = threadIdx.x >> 6;
  const int qbase = blockIdx.x * 16 + wv * 4;   // 4 queries per wave

  // this lane's 4 PH channels: 4*lane .. 4*lane+3
  const float4 bp0 = *(const float4*)&b_p0[4 * lane];
  // w_p1 rows for our channels (reused across the 4 queries)
  float wp1r[4][3];
#pragma unroll
  for (int r = 0; r < 4; ++r)
#pragma unroll
    for (int c = 0; c < 3; ++c) wp1r[r][c] = w_p1[(4 * lane + r) * 3 + c];

  const float d0v = dec[(size_t)(qbase + 0) * 64 + lane];
  const float d1v = dec[(size_t)(qbase + 1) * 64 + lane];
  const float d2v = dec[(size_t)(qbase + 2) * 64 + lane];
  const float d3v = dec[(size_t)(qbase + 3) * 64 + lane];

  float4 p0 = bp0, p1 = bp0, p2 = bp0, p3 = bp0;
#pragma unroll
  for (int i = 0; i < 64; ++i) {
    const float4 wv4 = *(const float4*)&w_p0[i * 256 + 4 * lane];
    const float s0 = rlane(d0v, i);
    const float s1 = rlane(d1v, i);
    const float s2 = rlane(d2v, i);
    const float s3 = rlane(d3v, i);
    p0.x = fmaf(s0, wv4.x, p0.x); p0.y = fmaf(s0, wv4.y, p0.y);
    p0.z = fmaf(s0, wv4.z, p0.z); p0.w = fmaf(s0, wv4.w, p0.w);
    p1.x = fmaf(s1, wv4.x, p1.x); p1.y = fmaf(s1, wv4.y, p1.y);
    p1.z = fmaf(s1, wv4.z, p1.z); p1.w = fmaf(s1, wv4.w, p1.w);
    p2.x = fmaf(s2, wv4.x, p2.x); p2.y = fmaf(s2, wv4.y, p2.y);
    p2.z = fmaf(s2, wv4.z, p2.z); p2.w = fmaf(s2, wv4.w, p2.w);
    p3.x = fmaf(s3, wv4.x, p3.x); p3.y = fmaf(s3, wv4.y, p3.y);
    p3.z = fmaf(s3, wv4.z, p3.z); p3.w = fmaf(s3, wv4.w, p3.w);
  }

  float4 g[4];
  g[0] = p0; g[1] = p1; g[2] = p2; g[3] = p3;
#pragma unroll
  for (int q = 0; q < 4; ++q) {
    g[q].x = gelu_exact(g[q].x); g[q].y = gelu_exact(g[q].y);
    g[q].z = gelu_exact(g[q].z); g[q].w = gelu_exact(g[q].w);
  }

#pragma unroll
  for (int q = 0; q < 4; ++q) {
#pragma unroll
    for (int c = 0; c < 3; ++c) {
      float v = g[q].x * wp1r[0][c] + g[q].y * wp1r[1][c] +
                g[q].z * wp1r[2][c] + g[q].w * wp1r[3][c];
#pragma unroll
      for (int off = 32; off > 0; off >>= 1) v += __shfl_xor(v, off);
      if (lane == 0) out[(size_t)(qbase + q) * 3 + c] = v + b_p1[c];
    }
  }
}

extern "C" void kernel_launch(void* const* d_in, const int* in_sizes, int n_in,
                              void* d_out, int out_size, void* d_ws, size_t ws_size,
                              hipStream_t stream) {
  const float* lat   = (const float*)d_in[0];
  const float* rn    = (const float*)d_in[1];
  const float* qc    = (const float*)d_in[2];
  const float* w_e0  = (const float*)d_in[3];
  const float* b_e0  = (const float*)d_in[4];
  const float* w_e1  = (const float*)d_in[5];
  const float* b_e1  = (const float*)d_in[6];
  const float* w_e2  = (const float*)d_in[7];
  const float* b_e2  = (const float*)d_in[8];
  const float* w_sw0 = (const float*)d_in[9];
  const float* b_sw0 = (const float*)d_in[10];
  const float* w_sw1 = (const float*)d_in[11];
  const float* b_sw1 = (const float*)d_in[12];
  const float* w_p0  = (const float*)d_in[13];
  const float* b_p0  = (const float*)d_in[14];
  const float* w_p1  = (const float*)d_in[15];
  const float* b_p1  = (const float*)d_in[16];

  float* dec = (float*)d_ws;            // [B*NQ,64] fp32 = 8 MB scratch
  float* out = (float*)d_out;           // [B*NQ,3] fp32

  hipLaunchKernelGGL(magno_main, dim3(NBATCH * NQRY), dim3(64), 0, stream,
                     lat, rn, qc, w_e0, b_e0, w_e1, b_e1, w_e2, b_e2,
                     w_sw0, b_sw0, w_sw1, b_sw1, dec);
  hipLaunchKernelGGL(magno_proj, dim3((NBATCH * NQRY) / 16), dim3(256), 0, stream,
                     dec, w_p0, b_p0, w_p1, b_p1, out);
}